// Round 7
// baseline (287.224 us; speedup 1.0000x reference)
//
#include <hip/hip_runtime.h>

typedef float  f32x4 __attribute__((ext_vector_type(4)));
typedef short  s16x8 __attribute__((ext_vector_type(8)));
typedef int    i32x4 __attribute__((ext_vector_type(4)));
typedef unsigned short u16x4 __attribute__((ext_vector_type(4)));
typedef unsigned int   u32x2 __attribute__((ext_vector_type(2)));

#define V_WORD   32000
#define DIM      128
#define LATENT   10000
#define NSPECIAL 4
#define NTOK     8192
#define NTILE    157        // ceil(10000/64)
#define BN       64
#define K0_BLOCKS 313       // ceil(10000/32)

__device__ __forceinline__ unsigned short f2bf(float f) {
  unsigned u = __builtin_bit_cast(unsigned, f);
  unsigned r = (u + 0x7fffu + ((u >> 16) & 1u)) >> 16;
  return (unsigned short)r;
}

__device__ __forceinline__ unsigned cvt_pk_bf16(float lo, float hi) {
  unsigned r;
  asm("v_cvt_pk_bf16_f32 %0, %1, %2" : "=v"(r) : "v"(lo), "v"(hi));
  return r;
}

__device__ __forceinline__ float tanh_fast(float x) {
  float t = __expf(2.f * x);
  return (t - 1.f) * __frcp_rn(t + 1.f);
}

// ---------------- K01: fused {latent convert+transpose} + {EmbeddingBag+tanh} ----------------
// blocks [0, K0_BLOCKS): 32-lat convert tile (fp32 -> Lb row-major + LTb transposed)
// blocks [K0_BLOCKS, +NTOK/4): one wave per token, bag of 26 + tanh
__global__ __launch_bounds__(256) void k01_prep(
    const float* __restrict__ latent, unsigned short* __restrict__ Lb,
    unsigned short* __restrict__ LTb,
    const float* __restrict__ ngram_emb, const int* __restrict__ ids,
    const int* __restrict__ offs, const int* __restrict__ x,
    float* __restrict__ langf, unsigned short* __restrict__ langb) {
  __shared__ float tile[32][129];
  int bid = blockIdx.x;
  int tid = threadIdx.x;
  if (bid < K0_BLOCKS) {
    // ---- convert/transpose 32 latent rows ----
    int l0 = bid * 32;
    int r  = tid >> 3;               // 0..31
    int c0 = (tid & 7) * 16;
    int l  = l0 + r;
    for (int k = 0; k < 4; ++k) {
      int d = c0 + k * 4;
      f32x4 v = {0.f, 0.f, 0.f, 0.f};
      if (l < LATENT) v = *reinterpret_cast<const f32x4*>(latent + (size_t)l * DIM + d);
      tile[r][d + 0] = v[0]; tile[r][d + 1] = v[1];
      tile[r][d + 2] = v[2]; tile[r][d + 3] = v[3];
      if (l < LATENT) {
        u16x4 o = { f2bf(v[0]), f2bf(v[1]), f2bf(v[2]), f2bf(v[3]) };
        *reinterpret_cast<u16x4*>(Lb + (size_t)l * DIM + d) = o;
      }
    }
    __syncthreads();
    int d = tid >> 1;                // 0..127
    int lbase = (tid & 1) * 16;
    for (int k = 0; k < 8; ++k) {
      int ll = lbase + 2 * k;
      int l1 = l0 + ll;
      if (l1 < LATENT) {             // LATENT even, l1 even -> pair always valid
        unsigned pack = (unsigned)f2bf(tile[ll][d]) | ((unsigned)f2bf(tile[ll + 1][d]) << 16);
        *reinterpret_cast<unsigned*>(LTb + (size_t)d * LATENT + l1) = pack;
      }
    }
  } else {
    // ---- bag + tanh: one wave per token ----
    int tok  = (bid - K0_BLOCKS) * 4 + (tid >> 6);
    int lane = tid & 63;
    int half = lane >> 5;            // 0: even rows, 1: odd rows
    int l32  = lane & 31;            // dims l32*4 .. +4
    int w = x[tok];
    f32x4 s0 = {0.f, 0.f, 0.f, 0.f}, s1 = {0.f, 0.f, 0.f, 0.f};
    if (w >= NSPECIAL) {
      int base = offs[w - NSPECIAL];
#pragma unroll
      for (int j = 0; j < 24; j += 4) {
        int ia = ids[base + j + half];
        int ib = ids[base + j + 2 + half];
        s0 += *reinterpret_cast<const f32x4*>(ngram_emb + (size_t)ia * DIM + l32 * 4);
        s1 += *reinterpret_cast<const f32x4*>(ngram_emb + (size_t)ib * DIM + l32 * 4);
      }
      int ic = ids[base + 24 + half];
      s0 += *reinterpret_cast<const f32x4*>(ngram_emb + (size_t)ic * DIM + l32 * 4);
      s0 += s1;
      for (int c = 0; c < 4; ++c) s0[c] += __shfl_xor(s0[c], 32, 64);
      for (int c = 0; c < 4; ++c) s0[c] = tanh_fast(s0[c]);
    }
    if (half == 0) {
      *reinterpret_cast<f32x4*>(langf + (size_t)tok * DIM + l32 * 4) = s0;
    } else {
      u32x2 pw = { cvt_pk_bf16(s0[0], s0[1]), cvt_pk_bf16(s0[2], s0[3]) };
      *reinterpret_cast<u32x2*>(langb + (size_t)tok * DIM + l32 * 4) = pw;
    }
  }
}

// ---------------- K2: fused softmax-attention over latent codebook ----------------
// grid = 64 token-blocks (BM=128) x nsplit latent splits; 4 waves/block.
// nsplit=16: split = xcd*2 + idx/64 -> per-XCD L2-resident slices; 3 LDS-resident blocks/CU.
// T14 async-stage: tile t+1's global loads issue under tile t's compute.
__global__ __launch_bounds__(256, 3) void k2_fused(
    const unsigned short* __restrict__ Lb,    // [LATENT][DIM]
    const unsigned short* __restrict__ LTb,   // [DIM][LATENT]
    const unsigned short* __restrict__ langb, // [NTOK][DIM]
    float* __restrict__ Opart,                // [nsplit][NTOK][DIM] (unnormalized)
    float* __restrict__ Zpart,                // [nsplit][NTOK]
    int nsplit) {
  __shared__ alignas(16) unsigned short Lsh[64 * DIM];    // [lat][dim], chunk-swizzled
  __shared__ alignas(16) unsigned short LTsh[DIM * 64];   // [dim][lat], chunk-swizzled
  __shared__ alignas(16) unsigned short Psh[128 * 64];    // [row][lat], chunk-swizzled
  __shared__ float zsh[128];

  int bid = blockIdx.x;
  int xcd = bid & 7, idx = bid >> 3;
  int split, tokblk;
  if (nsplit == 16)     { split = xcd * 2 + (idx >> 6);  tokblk = idx & 63; }
  else if (nsplit == 8) { split = xcd;                   tokblk = idx; }
  else                  { split = xcd >> 1;              tokblk = idx + ((xcd & 1) << 5); }
  int tokbase = tokblk * 128;
  int t0 = (split * NTILE) / nsplit, t1 = ((split + 1) * NTILE) / nsplit;
  int lat_s = t0 * BN;
  int lat_e = min(t1 * BN, LATENT);
  int ntiles = t1 - t0;
  int npad = t1 * BN - lat_e;        // pad lats score 0 -> P=1 -> subtract from Z

  int tid = threadIdx.x;
  int wid = tid >> 6, lane = tid & 63;
  int lr = lane & 15, lg = lane >> 4;
  int wm = wid & 1, wn = wid >> 1;   // GEMM1: lats wm*32..+32, rows wn*64..+64
                                     // GEMM2: rows wm*64..+64, dims wn*64..+64

  // per-thread staging geometry (constant across tiles; rows step by 16/32)
  int rL  = tid >> 4, csL = tid & 15;
  int coL = csL ^ (rL & 7);          // (rL+16i)&7 == rL&7
  int ddT = tid >> 3, csT = tid & 7;
  int coT = csT ^ (ddT & 7);

  // lang B-fragments live in registers for the whole kernel (64 VGPR)
  s16x8 Bl[4][4];
  for (int n = 0; n < 4; ++n) {
    int row = tokbase + wn * 64 + n * 16 + lr;
    for (int kf = 0; kf < 4; ++kf)
      Bl[n][kf] = *reinterpret_cast<const s16x8*>(langb + (size_t)row * DIM + (kf * 4 + lg) * 8);
  }

  f32x4 acc2[4][4];
  for (int a = 0; a < 4; ++a)
    for (int b = 0; b < 4; ++b) acc2[a][b] = {0.f, 0.f, 0.f, 0.f};
  float zp[4] = {0.f, 0.f, 0.f, 0.f};

  i32x4 stgL[4], stgT[4];            // in-flight staging registers (32 VGPR)
  auto prefetch = [&](int t) {
    int lat0 = lat_s + t * BN;
#pragma unroll
    for (int i = 0; i < 4; ++i) {
      int r = rL + i * 16;
      i32x4 v = {0, 0, 0, 0};
      if (lat0 + r < lat_e)
        v = *reinterpret_cast<const i32x4*>(Lb + (size_t)(lat0 + r) * DIM + coL * 8);
      stgL[i] = v;
    }
    bool okT = (lat0 + coT * 8 + 8 <= lat_e);   // tails are 8-lat aligned
#pragma unroll
    for (int i = 0; i < 4; ++i) {
      int dd = ddT + i * 32;
      i32x4 v = {0, 0, 0, 0};
      if (okT)
        v = *reinterpret_cast<const i32x4*>(LTb + (size_t)dd * LATENT + lat0 + coT * 8);
      stgT[i] = v;
    }
  };

  prefetch(0);

  for (int t = 0; t < ntiles; ++t) {
    // commit staged regs to LDS (compiler inserts vmcnt wait)
#pragma unroll
    for (int i = 0; i < 4; ++i)
      *reinterpret_cast<i32x4*>(&Lsh[(rL + i * 16) * DIM + csL * 8]) = stgL[i];
#pragma unroll
    for (int i = 0; i < 4; ++i)
      *reinterpret_cast<i32x4*>(&LTsh[(ddT + i * 32) * 64 + csT * 8]) = stgT[i];
    __syncthreads();

    // issue next tile's global loads early: latency hides under GEMM1+exp+GEMM2
    if (t + 1 < ntiles) prefetch(t + 1);

    // GEMM1 (swapped QK^T): S^T[lat][row] = sum_d latent[lat][d]*lang[row][d]
    f32x4 acc1[2][4];
    for (int m = 0; m < 2; ++m)
      for (int n = 0; n < 4; ++n) acc1[m][n] = {0.f, 0.f, 0.f, 0.f};
    for (int kf = 0; kf < 4; ++kf) {
      s16x8 a[2];
      for (int m = 0; m < 2; ++m) {
        int row = wm * 32 + m * 16 + lr;
        int c = kf * 4 + lg;
        a[m] = *reinterpret_cast<const s16x8*>(&Lsh[row * DIM + (c ^ (row & 7)) * 8]);
      }
      __builtin_amdgcn_s_setprio(1);
      for (int m = 0; m < 2; ++m)
        for (int n = 0; n < 4; ++n)
          acc1[m][n] = __builtin_amdgcn_mfma_f32_16x16x32_bf16(a[m], Bl[n][kf], acc1[m][n], 0, 0, 0);
      __builtin_amdgcn_s_setprio(0);
    }

    // exp (no max: |s| <= ~8 hard bound; pads exp(0)=1 corrected via npad), Z, pack P
    for (int m = 0; m < 2; ++m) {
      int la0 = wm * 32 + m * 16 + lg * 4;
      for (int n = 0; n < 4; ++n) {
        f32x4 v = acc1[m][n];
        float p0 = __expf(v[0]), p1 = __expf(v[1]);
        float p2 = __expf(v[2]), p3 = __expf(v[3]);
        zp[n] += p0; zp[n] += p1; zp[n] += p2; zp[n] += p3;
        u32x2 pw = { cvt_pk_bf16(p0, p1), cvt_pk_bf16(p2, p3) };
        int row = wn * 64 + n * 16 + lr;
        int c = la0 >> 3;
        *reinterpret_cast<u32x2*>(&Psh[row * 64 + ((c ^ (row & 7)) << 3) + (la0 & 7)]) = pw;
      }
    }
    __syncthreads();

    // GEMM2: O[row][dim] += P[row][lat] * latent[lat][dim]
    for (int kf = 0; kf < 2; ++kf) {
      s16x8 Ap[4], Bt[4];
      int c = kf * 4 + lg;
      for (int mr = 0; mr < 4; ++mr) {
        int row = wm * 64 + mr * 16 + lr;
        Ap[mr] = *reinterpret_cast<const s16x8*>(&Psh[row * 64 + ((c ^ (row & 7)) << 3)]);
      }
      for (int nd = 0; nd < 4; ++nd) {
        int dr = wn * 64 + nd * 16 + lr;
        Bt[nd] = *reinterpret_cast<const s16x8*>(&LTsh[dr * 64 + ((c ^ (dr & 7)) << 3)]);
      }
      __builtin_amdgcn_s_setprio(1);
      for (int mr = 0; mr < 4; ++mr)
        for (int nd = 0; nd < 4; ++nd)
          acc2[mr][nd] = __builtin_amdgcn_mfma_f32_16x16x32_bf16(Ap[mr], Bt[nd], acc2[mr][nd], 0, 0, 0);
      __builtin_amdgcn_s_setprio(0);
    }
    __syncthreads();
  }

  // Z: butterfly over lat lane-groups, then combine the two wm halves via LDS
  for (int n = 0; n < 4; ++n) {
    zp[n] += __shfl_xor(zp[n], 16, 64);
    zp[n] += __shfl_xor(zp[n], 32, 64);
  }
  if (wm == 0 && lane < 16)
    for (int n = 0; n < 4; ++n) zsh[wn * 64 + n * 16 + lr] = zp[n];
  __syncthreads();
  if (wm == 1 && lane < 16)
    for (int n = 0; n < 4; ++n) zsh[wn * 64 + n * 16 + lr] += zp[n];
  __syncthreads();

  for (int mr = 0; mr < 4; ++mr) {
    int rbase = wm * 64 + mr * 16 + lg * 4;
    for (int nd = 0; nd < 4; ++nd) {
      int dcol = wn * 64 + nd * 16 + lr;
      for (int i = 0; i < 4; ++i) {
        int row = rbase + i;
        Opart[((size_t)split * NTOK + tokbase + row) * DIM + dcol] = acc2[mr][nd][i];
      }
    }
  }
  if (tid < 128)
    Zpart[split * NTOK + tokbase + tid] = zsh[tid] - (float)npad;
}

// ---------------- K3: combine splits, add lang, override specials ----------------
__global__ __launch_bounds__(256) void k3_combine(
    const float* __restrict__ special, const int* __restrict__ x,
    const float* __restrict__ langf, const float* __restrict__ Opart,
    const float* __restrict__ Zpart, float* __restrict__ out, int nsplit) {
  int gi  = blockIdx.x * 256 + threadIdx.x;  // float4 units
  int tok = gi >> 5;
  int d4  = (gi & 31) * 4;
  int w   = x[tok];
  f32x4 o;
  if (w < NSPECIAL) {
    o = *reinterpret_cast<const f32x4*>(special + (size_t)w * DIM + d4);
  } else {
    f32x4 s = {0.f, 0.f, 0.f, 0.f};
    float z = 0.f;
    for (int sp = 0; sp < nsplit; ++sp) {
      s += *reinterpret_cast<const f32x4*>(Opart + ((size_t)sp * NTOK + tok) * DIM + d4);
      z += Zpart[sp * NTOK + tok];
    }
    f32x4 lg = *reinterpret_cast<const f32x4*>(langf + (size_t)tok * DIM + d4);
    o = lg + s / z;
  }
  *reinterpret_cast<f32x4*>(out + (size_t)tok * DIM + d4) = o;
}

extern "C" void kernel_launch(void* const* d_in, const int* in_sizes, int n_in,
                              void* d_out, int out_size, void* d_ws, size_t ws_size,
                              hipStream_t stream) {
  const float* ngram_emb = (const float*)d_in[0];
  const float* latent    = (const float*)d_in[1];
  const float* special   = (const float*)d_in[2];
  const int*   ids       = (const int*)d_in[3];
  const int*   offs      = (const int*)d_in[4];
  const int*   x         = (const int*)d_in[5];
  float* out = (float*)d_out;

  size_t fixed = (size_t)LATENT * DIM * 2 * 2      // Lb + LTb
               + (size_t)NTOK * DIM * 4            // langf
               + (size_t)NTOK * DIM * 2;           // langb
  int nsplit = 16;
  while (nsplit > 4) {
    size_t need = fixed + (size_t)nsplit * NTOK * DIM * 4 + (size_t)nsplit * NTOK * 4;
    if (need <= ws_size) break;
    nsplit >>= 1;
  }

  char* w = (char*)d_ws;
  unsigned short* Lb  = (unsigned short*)w;  w += (size_t)LATENT * DIM * 2;
  unsigned short* LTb = (unsigned short*)w;  w += (size_t)DIM * LATENT * 2;
  float* langf        = (float*)w;           w += (size_t)NTOK * DIM * 4;
  unsigned short* langb = (unsigned short*)w; w += (size_t)NTOK * DIM * 2;
  float* Opart        = (float*)w;           w += (size_t)nsplit * NTOK * DIM * 4;
  float* Zpart        = (float*)w;           w += (size_t)nsplit * NTOK * 4;

  hipLaunchKernelGGL(k01_prep, dim3(K0_BLOCKS + NTOK / 4), dim3(256), 0, stream,
                     latent, Lb, LTb, ngram_emb, ids, offs, x, langf, langb);
  hipLaunchKernelGGL(k2_fused, dim3(nsplit * 64), dim3(256), 0, stream,
                     Lb, LTb, langb, Opart, Zpart, nsplit);
  hipLaunchKernelGGL(k3_combine, dim3(NTOK * DIM / 4 / 256), dim3(256), 0, stream,
                     special, x, langf, Opart, Zpart, out, nsplit);
}

// Round 8
// 140.619 us; speedup vs baseline: 2.0426x; 2.0426x over previous
//
#include <hip/hip_runtime.h>

typedef float  f32x4 __attribute__((ext_vector_type(4)));
typedef short  s16x8 __attribute__((ext_vector_type(8)));
typedef int    i32x4 __attribute__((ext_vector_type(4)));
typedef unsigned short u16x4 __attribute__((ext_vector_type(4)));
typedef unsigned int   u32x2 __attribute__((ext_vector_type(2)));

#define V_WORD   32000
#define DIM      128
#define LATENT   10000
#define LATP     10048      // padded to 157*64; pad rows/cols are ZERO
#define NSPECIAL 4
#define NTOK     8192
#define NTILE    157
#define BN       64
#define K0_BLOCKS 314       // ceil(10048/32)

__device__ __forceinline__ unsigned short f2bf(float f) {
  unsigned u = __builtin_bit_cast(unsigned, f);
  unsigned r = (u + 0x7fffu + ((u >> 16) & 1u)) >> 16;
  return (unsigned short)r;
}

__device__ __forceinline__ unsigned cvt_pk_bf16(float lo, float hi) {
  unsigned r;
  asm("v_cvt_pk_bf16_f32 %0, %1, %2" : "=v"(r) : "v"(lo), "v"(hi));
  return r;
}

__device__ __forceinline__ float tanh_fast(float x) {
  float t = __expf(2.f * x);
  return (t - 1.f) * __frcp_rn(t + 1.f);
}

__device__ __forceinline__ void gload_lds16(const void* g, void* l) {
  __builtin_amdgcn_global_load_lds(
      (const __attribute__((address_space(1))) void*)g,
      (__attribute__((address_space(3))) void*)l, 16, 0, 0);
}

// ---------------- K01: fused {latent convert+transpose (zero-padded)} + {bag+tanh} ----------------
__global__ __launch_bounds__(256) void k01_prep(
    const float* __restrict__ latent, unsigned short* __restrict__ Lb,
    unsigned short* __restrict__ LTb,
    const float* __restrict__ ngram_emb, const int* __restrict__ ids,
    const int* __restrict__ offs, const int* __restrict__ x,
    float* __restrict__ langf, unsigned short* __restrict__ langb) {
  __shared__ float tile[32][129];
  int bid = blockIdx.x;
  int tid = threadIdx.x;
  if (bid < K0_BLOCKS) {
    // ---- convert/transpose 32 latent rows (rows >= LATENT written as zeros) ----
    int l0 = bid * 32;
    int r  = tid >> 3;               // 0..31
    int c0 = (tid & 7) * 16;
    int l  = l0 + r;
    for (int k = 0; k < 4; ++k) {
      int d = c0 + k * 4;
      f32x4 v = {0.f, 0.f, 0.f, 0.f};
      if (l < LATENT) v = *reinterpret_cast<const f32x4*>(latent + (size_t)l * DIM + d);
      tile[r][d + 0] = v[0]; tile[r][d + 1] = v[1];
      tile[r][d + 2] = v[2]; tile[r][d + 3] = v[3];
      u16x4 o = { f2bf(v[0]), f2bf(v[1]), f2bf(v[2]), f2bf(v[3]) };
      *reinterpret_cast<u16x4*>(Lb + (size_t)l * DIM + d) = o;
    }
    __syncthreads();
    int d = tid >> 1;                // 0..127
    int lbase = (tid & 1) * 16;
    for (int k = 0; k < 8; ++k) {
      int ll = lbase + 2 * k;
      int l1 = l0 + ll;
      unsigned pack = (unsigned)f2bf(tile[ll][d]) | ((unsigned)f2bf(tile[ll + 1][d]) << 16);
      *reinterpret_cast<unsigned*>(LTb + (size_t)d * LATP + l1) = pack;
    }
  } else {
    // ---- bag + tanh: one wave per token ----
    int tok  = (bid - K0_BLOCKS) * 4 + (tid >> 6);
    int lane = tid & 63;
    int half = lane >> 5;            // 0: even rows, 1: odd rows
    int l32  = lane & 31;            // dims l32*4 .. +4
    int w = x[tok];
    f32x4 s0 = {0.f, 0.f, 0.f, 0.f}, s1 = {0.f, 0.f, 0.f, 0.f};
    if (w >= NSPECIAL) {
      int base = offs[w - NSPECIAL];
#pragma unroll
      for (int j = 0; j < 24; j += 4) {
        int ia = ids[base + j + half];
        int ib = ids[base + j + 2 + half];
        s0 += *reinterpret_cast<const f32x4*>(ngram_emb + (size_t)ia * DIM + l32 * 4);
        s1 += *reinterpret_cast<const f32x4*>(ngram_emb + (size_t)ib * DIM + l32 * 4);
      }
      int ic = ids[base + 24 + half];
      s0 += *reinterpret_cast<const f32x4*>(ngram_emb + (size_t)ic * DIM + l32 * 4);
      s0 += s1;
      for (int c = 0; c < 4; ++c) s0[c] += __shfl_xor(s0[c], 32, 64);
      for (int c = 0; c < 4; ++c) s0[c] = tanh_fast(s0[c]);
    }
    if (half == 0) {
      *reinterpret_cast<f32x4*>(langf + (size_t)tok * DIM + l32 * 4) = s0;
    } else {
      u32x2 pw = { cvt_pk_bf16(s0[0], s0[1]), cvt_pk_bf16(s0[2], s0[3]) };
      *reinterpret_cast<u32x2*>(langb + (size_t)tok * DIM + l32 * 4) = pw;
    }
  }
}

// ---------------- K2: fused softmax-attention over latent codebook ----------------
// grid = 64 token-blocks x nsplit=8 latent splits = 512 blocks = 2/CU resident.
// Staging: double-buffered global_load_lds (dest linear = tid*16B; swizzle carried
// on the pre-swizzled GLOBAL source address). Loads for tile t+1 are issued right
// after the loop-top barrier and drain only at the next loop top.
__global__ __launch_bounds__(256, 2) void k2_fused(
    const unsigned short* __restrict__ Lb,    // [LATP][DIM], pad rows zero
    const unsigned short* __restrict__ LTb,   // [DIM][LATP], pad cols zero
    const unsigned short* __restrict__ langb, // [NTOK][DIM]
    float* __restrict__ Opart,                // [nsplit][NTOK][DIM]
    float* __restrict__ Zpart,                // [nsplit][NTOK]
    int nsplit) {
  // 80 KB total: Lsh[2][16KB] | LTsh[2][16KB] | Psh[16KB] (zsh aliases Psh)
  __shared__ alignas(16) unsigned short smem[5 * 8192];
  unsigned short* Psh = smem + 4 * 8192;
  float* zsh = (float*)Psh;                  // alias; used only after Psh is dead

  int bid = blockIdx.x;
  int xcd = bid & 7, idx = bid >> 3;
  int split, tokblk;
  if (nsplit == 8)      { split = xcd;                   tokblk = idx; }
  else if (nsplit == 16){ split = xcd * 2 + (idx >> 6);  tokblk = idx & 63; }
  else                  { split = xcd >> 1;              tokblk = idx + ((xcd & 1) << 5); }
  int tokbase = tokblk * 128;
  int t0 = (split * NTILE) / nsplit, t1 = ((split + 1) * NTILE) / nsplit;
  int lat_s = t0 * BN;
  int ntiles = t1 - t0;
  int npad = max(0, t1 * BN - LATENT);       // pad lats score 0 -> exp=1 -> subtract

  int tid = threadIdx.x;
  int wid = tid >> 6, lane = tid & 63;
  int lr = lane & 15, lg = lane >> 4;
  int wm = wid & 1, wn = wid >> 1;   // GEMM1: lats wm*32..+32, rows wn*64..+64
                                     // GEMM2: rows wm*64..+64, dims wn*64..+64

  // staging geometry: dest byte offset = (i*256+tid)*16 (linear); swizzle on source
  int rL  = tid >> 4, csL = tid & 15;
  int coL = csL ^ (rL & 7);
  int ddT = tid >> 3, csT = tid & 7;
  int coT = csT ^ (ddT & 7);
  const unsigned short* srcL0 = Lb + (size_t)rL * DIM + coL * 8;   // + (lat0)*DIM + i*16*DIM
  const unsigned short* srcT0 = LTb + (size_t)ddT * LATP + coT * 8; // + lat0 + i*32*LATP
  int wbase = wid * 64 * 8;          // wave-uniform LDS element base within a chunk

  auto issue = [&](int buf, int t) {
    int lat0 = lat_s + t * BN;
    const unsigned short* sL = srcL0 + (size_t)lat0 * DIM;
    const unsigned short* sT = srcT0 + lat0;
    unsigned short* dL = smem + buf * 8192 + wbase;
    unsigned short* dT = smem + 16384 + buf * 8192 + wbase;
#pragma unroll
    for (int i = 0; i < 4; ++i)
      gload_lds16(sL + (size_t)i * 16 * DIM, dL + i * 2048);
#pragma unroll
    for (int i = 0; i < 4; ++i)
      gload_lds16(sT + (size_t)i * 32 * LATP, dT + i * 2048);
  };

  // lang B-fragments live in registers for the whole kernel (64 VGPR)
  s16x8 Bl[4][4];
  for (int n = 0; n < 4; ++n) {
    int row = tokbase + wn * 64 + n * 16 + lr;
    for (int kf = 0; kf < 4; ++kf)
      Bl[n][kf] = *reinterpret_cast<const s16x8*>(langb + (size_t)row * DIM + (kf * 4 + lg) * 8);
  }

  f32x4 acc2[4][4];
  for (int a = 0; a < 4; ++a)
    for (int b = 0; b < 4; ++b) acc2[a][b] = {0.f, 0.f, 0.f, 0.f};
  float zp[4] = {0.f, 0.f, 0.f, 0.f};

  issue(0, 0);
  int cur = 0;

  for (int t = 0; t < ntiles; ++t) {
    asm volatile("s_waitcnt vmcnt(0)" ::: "memory");
    __syncthreads();                 // buf[cur] ready; buf[cur^1] free
    if (t + 1 < ntiles) issue(cur ^ 1, t + 1);

    const unsigned short* Lsh  = smem + cur * 8192;
    const unsigned short* LTsh = smem + 16384 + cur * 8192;

    // GEMM1 (swapped QK^T): S^T[lat][row] = sum_d latent[lat][d]*lang[row][d]
    f32x4 acc1[2][4];
    for (int m = 0; m < 2; ++m)
      for (int n = 0; n < 4; ++n) acc1[m][n] = {0.f, 0.f, 0.f, 0.f};
    for (int kf = 0; kf < 4; ++kf) {
      s16x8 a[2];
      for (int m = 0; m < 2; ++m) {
        int row = wm * 32 + m * 16 + lr;
        int c = kf * 4 + lg;
        a[m] = *reinterpret_cast<const s16x8*>(&Lsh[row * DIM + (c ^ (row & 7)) * 8]);
      }
      __builtin_amdgcn_s_setprio(1);
      for (int m = 0; m < 2; ++m)
        for (int n = 0; n < 4; ++n)
          acc1[m][n] = __builtin_amdgcn_mfma_f32_16x16x32_bf16(a[m], Bl[n][kf], acc1[m][n], 0, 0, 0);
      __builtin_amdgcn_s_setprio(0);
    }

    // exp (no max: |s| <= ~8 hard bound; pad lats give exp(0)=1, fixed via npad)
    for (int m = 0; m < 2; ++m) {
      int la0 = wm * 32 + m * 16 + lg * 4;
      for (int n = 0; n < 4; ++n) {
        f32x4 v = acc1[m][n];
        float p0 = __expf(v[0]), p1 = __expf(v[1]);
        float p2 = __expf(v[2]), p3 = __expf(v[3]);
        zp[n] += p0; zp[n] += p1; zp[n] += p2; zp[n] += p3;
        u32x2 pw = { cvt_pk_bf16(p0, p1), cvt_pk_bf16(p2, p3) };
        int row = wn * 64 + n * 16 + lr;
        int c = la0 >> 3;
        *reinterpret_cast<u32x2*>(&Psh[row * 64 + ((c ^ (row & 7)) << 3) + (la0 & 7)]) = pw;
      }
    }
    __syncthreads();                 // Psh ready

    // GEMM2: O[row][dim] += P[row][lat] * latent[lat][dim]
    for (int kf = 0; kf < 2; ++kf) {
      s16x8 Ap[4], Bt[4];
      int c = kf * 4 + lg;
      for (int mr = 0; mr < 4; ++mr) {
        int row = wm * 64 + mr * 16 + lr;
        Ap[mr] = *reinterpret_cast<const s16x8*>(&Psh[row * 64 + ((c ^ (row & 7)) << 3)]);
      }
      for (int nd = 0; nd < 4; ++nd) {
        int dr = wn * 64 + nd * 16 + lr;
        Bt[nd] = *reinterpret_cast<const s16x8*>(&LTsh[dr * 64 + ((c ^ (dr & 7)) << 3)]);
      }
      __builtin_amdgcn_s_setprio(1);
      for (int mr = 0; mr < 4; ++mr)
        for (int nd = 0; nd < 4; ++nd)
          acc2[mr][nd] = __builtin_amdgcn_mfma_f32_16x16x32_bf16(Ap[mr], Bt[nd], acc2[mr][nd], 0, 0, 0);
      __builtin_amdgcn_s_setprio(0);
    }
    cur ^= 1;
  }

  __syncthreads();                   // Psh dead -> zsh alias safe

  // Z: butterfly over lat lane-groups, then combine the two wm halves via LDS
  for (int n = 0; n < 4; ++n) {
    zp[n] += __shfl_xor(zp[n], 16, 64);
    zp[n] += __shfl_xor(zp[n], 32, 64);
  }
  if (wm == 0 && lane < 16)
    for (int n = 0; n < 4; ++n) zsh[wn * 64 + n * 16 + lr] = zp[n];
  __syncthreads();
  if (wm == 1 && lane < 16)
    for (int n = 0; n < 4; ++n) zsh[wn * 64 + n * 16 + lr] += zp[n];
  __syncthreads();

  for (int mr = 0; mr < 4; ++mr) {
    int rbase = wm * 64 + mr * 16 + lg * 4;
    for (int nd = 0; nd < 4; ++nd) {
      int dcol = wn * 64 + nd * 16 + lr;
      for (int i = 0; i < 4; ++i) {
        int row = rbase + i;
        Opart[((size_t)split * NTOK + tokbase + row) * DIM + dcol] = acc2[mr][nd][i];
      }
    }
  }
  if (tid < 128)
    Zpart[split * NTOK + tokbase + tid] = zsh[tid] - (float)npad;
}

// ---------------- K3: combine splits, add lang, override specials ----------------
__global__ __launch_bounds__(256) void k3_combine(
    const float* __restrict__ special, const int* __restrict__ x,
    const float* __restrict__ langf, const float* __restrict__ Opart,
    const float* __restrict__ Zpart, float* __restrict__ out, int nsplit) {
  int gi  = blockIdx.x * 256 + threadIdx.x;  // float4 units
  int tok = gi >> 5;
  int d4  = (gi & 31) * 4;
  int w   = x[tok];
  f32x4 o;
  if (w < NSPECIAL) {
    o = *reinterpret_cast<const f32x4*>(special + (size_t)w * DIM + d4);
  } else {
    f32x4 s = {0.f, 0.f, 0.f, 0.f};
    float z = 0.f;
    for (int sp = 0; sp < nsplit; ++sp) {
      s += *reinterpret_cast<const f32x4*>(Opart + ((size_t)sp * NTOK + tok) * DIM + d4);
      z += Zpart[sp * NTOK + tok];
    }
    f32x4 lg = *reinterpret_cast<const f32x4*>(langf + (size_t)tok * DIM + d4);
    o = lg + s / z;
  }
  *reinterpret_cast<f32x4*>(out + (size_t)tok * DIM + d4) = o;
}

extern "C" void kernel_launch(void* const* d_in, const int* in_sizes, int n_in,
                              void* d_out, int out_size, void* d_ws, size_t ws_size,
                              hipStream_t stream) {
  const float* ngram_emb = (const float*)d_in[0];
  const float* latent    = (const float*)d_in[1];
  const float* special   = (const float*)d_in[2];
  const int*   ids       = (const int*)d_in[3];
  const int*   offs      = (const int*)d_in[4];
  const int*   x         = (const int*)d_in[5];
  float* out = (float*)d_out;

  size_t fixed = (size_t)LATP * DIM * 2 * 2        // Lb + LTb (padded)
               + (size_t)NTOK * DIM * 4            // langf
               + (size_t)NTOK * DIM * 2;           // langb
  int nsplit = 8;
  while (nsplit > 4) {
    size_t need = fixed + (size_t)nsplit * NTOK * DIM * 4 + (size_t)nsplit * NTOK * 4;
    if (need <= ws_size) break;
    nsplit >>= 1;
  }

  char* w = (char*)d_ws;
  unsigned short* Lb  = (unsigned short*)w;  w += (size_t)LATP * DIM * 2;
  unsigned short* LTb = (unsigned short*)w;  w += (size_t)DIM * LATP * 2;
  float* langf        = (float*)w;           w += (size_t)NTOK * DIM * 4;
  unsigned short* langb = (unsigned short*)w; w += (size_t)NTOK * DIM * 2;
  float* Opart        = (float*)w;           w += (size_t)nsplit * NTOK * DIM * 4;
  float* Zpart        = (float*)w;           w += (size_t)nsplit * NTOK * 4;

  hipLaunchKernelGGL(k01_prep, dim3(K0_BLOCKS + NTOK / 4), dim3(256), 0, stream,
                     latent, Lb, LTb, ngram_emb, ids, offs, x, langf, langb);
  hipLaunchKernelGGL(k2_fused, dim3(nsplit * 64), dim3(256), 0, stream,
                     Lb, LTb, langb, Opart, Zpart, nsplit);
  hipLaunchKernelGGL(k3_combine, dim3(NTOK * DIM / 4 / 256), dim3(256), 0, stream,
                     special, x, langf, Opart, Zpart, out, nsplit);
}